// Round 4
// baseline (208.176 us; speedup 1.0000x reference)
//
#include <hip/hip_runtime.h>
#include <hip/hip_bf16.h>
#include <math.h>

#define N_NODES 50000
#define N_EDGES 800000
#define IN_CH 128
#define OUT_CH 64
#define BN_EPS 1e-5f
#define CAP 64  // max in-degree slots; P(deg>64) ~ e^-40 for 800k edges into 50k nodes

typedef __attribute__((ext_vector_type(8))) short short8;
typedef __attribute__((ext_vector_type(4))) float f32x4;

__device__ __forceinline__ float bf16u_to_f32(uint u) { return __uint_as_float(u << 16); }

__device__ __forceinline__ ushort f32_to_bf16(float f) {
    uint u = __float_as_uint(f);
    uint r = (u + 0x7fff + ((u >> 16) & 1)) >> 16;  // RNE
    return (ushort)r;
}

// tanh(x) = (e^2x - 1)/(e^2x + 1) via v_exp_f32 (2^x) + v_rcp_f32. ~1e-6 abs error,
// negligible vs the 0.0176 bf16 floor. Clamp arg: tanh(30)==1.0f in fp32, avoids inf/inf.
__device__ __forceinline__ float fast_tanh(float x) {
    float xa = fminf(x, 30.0f);
    float e;
    asm("v_exp_f32 %0, %1" : "=v"(e) : "v"(xa * 2.8853900817779268f));  // e^{2x} = 2^{2x*log2(e)}
    float inv;
    asm("v_rcp_f32 %0, %1" : "=v"(inv) : "v"(e + 1.0f));
    return (e - 1.0f) * inv;
}

// ---------------- fill slot table: slot[d*CAP + pos] = src (ushort) ----------------
// Plain stores: L2 merges the ~8 scattered 2B stores per 128B line (NT stores forced
// partial-line HBM writebacks -> 46MB WRITE_SIZE, +11us; reverted).
__global__ void fill_slots_kernel(const int4* __restrict__ esrc4, const int4* __restrict__ edst4,
                                  int* __restrict__ cnt, ushort* __restrict__ slot, int E4) {
    int i = blockIdx.x * blockDim.x + threadIdx.x;
    if (i < E4) {
        int4 s = esrc4[i];
        int4 d = edst4[i];
        int p;
        p = atomicAdd(&cnt[d.x], 1); if (p < CAP) slot[d.x * CAP + p] = (ushort)s.x;
        p = atomicAdd(&cnt[d.y], 1); if (p < CAP) slot[d.y * CAP + p] = (ushort)s.y;
        p = atomicAdd(&cnt[d.z], 1); if (p < CAP) slot[d.z * CAP + p] = (ushort)s.z;
        p = atomicAdd(&cnt[d.w], 1); if (p < CAP) slot[d.w * CAP + p] = (ushort)s.w;
    }
}

// ---------------- MFMA GEMM: hb[N,64](bf16) = bf16(x[N,128]) @ bf16(W[128,64]) * rsqrt(cnt+1) --
// dinv[src] folded into hb so the gather inner loop is a pure row-sum. dinv computed from cnt
// directly (rsqrtf is deterministic -> bitwise-identical to a precomputed array).
// XPAD=136: row stride = 17 x 16B granules (odd) -> ds_read_b128 conflict-free.
#define XPAD 136
__global__ __launch_bounds__(256) void gemm_mfma_kernel(const float* __restrict__ x,
                                                        const float* __restrict__ W,
                                                        const int* __restrict__ cnt,
                                                        ushort* __restrict__ hb, int N) {
    __shared__ ushort xs[64 * XPAD];
    __shared__ ushort wt[64 * XPAD];   // W^T: wt[n][k]
    int t = threadIdx.x;
    int lane = t & 63;
    int w = t >> 6;
    int nn = lane & 15;
    int quad = lane >> 4;
    int row0 = blockIdx.x * 64;

#pragma unroll
    for (int i = 0; i < 32; ++i) {
        int wlin = t + 256 * i;
        int k = wlin >> 6, n = wlin & 63;
        wt[n * XPAD + k] = f32_to_bf16(W[wlin]);
    }
#pragma unroll
    for (int i = 0; i < 8; ++i) {
        int linear4 = t + 256 * i;
        int r = linear4 >> 5;
        int c4 = linear4 & 31;
        int gr = row0 + r; if (gr >= N) gr = N - 1;
        float4 v = *(const float4*)(x + (size_t)gr * IN_CH + c4 * 4);
        ushort u0 = f32_to_bf16(v.x), u1 = f32_to_bf16(v.y);
        ushort u2 = f32_to_bf16(v.z), u3 = f32_to_bf16(v.w);
        uint2 packed = make_uint2((uint)u0 | ((uint)u1 << 16), (uint)u2 | ((uint)u3 << 16));
        *(uint2*)&xs[r * XPAD + c4 * 4] = packed;
    }
    __syncthreads();

    short8 bfrag[4][4];
#pragma unroll
    for (int t2 = 0; t2 < 4; ++t2)
#pragma unroll
        for (int c = 0; c < 4; ++c)
            bfrag[t2][c] = *(const short8*)&wt[(16 * t2 + nn) * XPAD + 32 * c + quad * 8];

    f32x4 acc[4] = {{0.f, 0.f, 0.f, 0.f}, {0.f, 0.f, 0.f, 0.f},
                    {0.f, 0.f, 0.f, 0.f}, {0.f, 0.f, 0.f, 0.f}};
#pragma unroll
    for (int c = 0; c < 4; ++c) {
        short8 afrag = *(const short8*)&xs[(16 * w + nn) * XPAD + 32 * c + quad * 8];
#pragma unroll
        for (int t2 = 0; t2 < 4; ++t2)
            acc[t2] = __builtin_amdgcn_mfma_f32_16x16x32_bf16(afrag, bfrag[t2][c], acc[t2], 0, 0, 0);
    }

    int rbase = row0 + 16 * w + quad * 4;
    float dv[4];
#pragma unroll
    for (int r = 0; r < 4; ++r)
        dv[r] = (rbase + r < N) ? rsqrtf((float)(cnt[rbase + r] + 1)) : 0.f;
#pragma unroll
    for (int t2 = 0; t2 < 4; ++t2) {
#pragma unroll
        for (int r = 0; r < 4; ++r) {
            int row = rbase + r;
            if (row < N) hb[(size_t)row * OUT_CH + 16 * t2 + nn] = f32_to_bf16(acc[t2][r] * dv[r]);
        }
    }
}

// ---------------- fused gather: 8 groups x 8 lanes, uint4 row loads (8 edges/instr) ----------
// One wave per dst node; next node's slot/cnt prefetched one node ahead (vmcnt waits the
// OLDEST load, so waiting on current sv leaves prefetches in flight). Item 0 = self-loop,
// items 1..m = slot entries; out-of-range items read zeroed row hb[N].
// NO __launch_bounds__ min-waves: a 64-VGPR cap made the allocator serialize the 2-deep
// ISSUE pipeline (VGPR 52->32, VALUBusy 30->16%, +9us). ILP > occupancy here.
__global__ __launch_bounds__(256) void gather_fused_kernel(const int* __restrict__ cnt,
                                                           const ushort* __restrict__ slot,
                                                           const ushort* __restrict__ hb,
                                                           const float* __restrict__ bias,
                                                           float* __restrict__ out,
                                                           float* __restrict__ sums, int N) {
    int t = threadIdx.x;
    int lane = t & 63;
    int g = lane >> 3;
    int sub = lane & 7;
    // channel this lane owns after the reducing exchange (3-bit reversal of g)
    int cidx = 8 * sub + (((g & 1) << 2) | (g & 2) | ((g >> 2) & 1));
    int wid = (blockIdx.x * blockDim.x + t) >> 6;
    int nw = (gridDim.x * blockDim.x) >> 6;
    float bias_c = bias[cidx];
    float ssum = 0.f, ssq = 0.f;

#define ISSUE(J, H0, H1) do {                                              \
        int e0 = (J) + g, e1 = e0 + 8;                                     \
        int i0 = e0 - 1; i0 = (i0 < 0) ? 0 : i0;                           \
        int s0 = __shfl(sv, i0);                                           \
        int s1 = __shfl(sv, e1 - 1);                                       \
        s0 = (e0 == 0) ? d : s0;                                           \
        s0 = (e0 < M) ? s0 : N_NODES;                                      \
        s1 = (e1 < M) ? s1 : N_NODES;                                      \
        H0 = *(const uint4*)(hb + ((size_t)s0 << 6) + (sub << 3));         \
        H1 = *(const uint4*)(hb + ((size_t)s1 << 6) + (sub << 3));         \
    } while (0)

#define CONSUME(H)                                                          \
        a0 += __uint_as_float((H).x << 16); a1 += __uint_as_float((H).x & 0xffff0000u); \
        a2 += __uint_as_float((H).y << 16); a3 += __uint_as_float((H).y & 0xffff0000u); \
        a4 += __uint_as_float((H).z << 16); a5 += __uint_as_float((H).z & 0xffff0000u); \
        a6 += __uint_as_float((H).w << 16); a7 += __uint_as_float((H).w & 0xffff0000u);

    int d = wid;
    int m_n = 0, sv_n = 0;
    if (d < N) {
        m_n = cnt[d];
        sv_n = __builtin_nontemporal_load(&slot[(size_t)d * CAP + lane]);
    }

    while (d < N) {
        int mraw = m_n;
        int sv = sv_n;
        float dd = rsqrtf((float)(mraw + 1));      // raw degree for normalization
        int m = mraw; if (m > CAP) m = CAP;        // clamp only for slot iteration
        int M = m + 1;  // +1: self-loop at item 0

        int dn = d + nw;
        if (dn < N) {  // prefetch next node while this one is processed
            m_n = cnt[dn];
            sv_n = __builtin_nontemporal_load(&slot[(size_t)dn * CAP + lane]);
        }

        float a0 = 0.f, a1 = 0.f, a2 = 0.f, a3 = 0.f;
        float a4 = 0.f, a5 = 0.f, a6 = 0.f, a7 = 0.f;

        uint4 h0, h1;
        ISSUE(0, h0, h1);
        for (int j = 16; j < M; j += 16) {
            uint4 n0, n1;
            ISSUE(j, n0, n1);           // next block's loads fly while we consume
            CONSUME(h0); CONSUME(h1);
            h0 = n0; h1 = n1;
        }
        CONSUME(h0); CONSUME(h1);

        // reducing exchange across the 8 groups: 3 xor rounds, ends with 1 channel/lane
        float b0, b1, b2, b3;
        {
            float s0 = a0 + __shfl_xor(a0, 8);
            float s1 = a1 + __shfl_xor(a1, 8);
            float s2 = a2 + __shfl_xor(a2, 8);
            float s3 = a3 + __shfl_xor(a3, 8);
            float s4 = a4 + __shfl_xor(a4, 8);
            float s5 = a5 + __shfl_xor(a5, 8);
            float s6 = a6 + __shfl_xor(a6, 8);
            float s7 = a7 + __shfl_xor(a7, 8);
            bool hi = (g & 1);
            b0 = hi ? s4 : s0; b1 = hi ? s5 : s1; b2 = hi ? s6 : s2; b3 = hi ? s7 : s3;
        }
        float c0, c1;
        {
            float s0 = b0 + __shfl_xor(b0, 16);
            float s1 = b1 + __shfl_xor(b1, 16);
            float s2 = b2 + __shfl_xor(b2, 16);
            float s3 = b3 + __shfl_xor(b3, 16);
            bool hi = (g & 2);
            c0 = hi ? s2 : s0; c1 = hi ? s3 : s1;
        }
        float total;
        {
            float s0 = c0 + __shfl_xor(c0, 32);
            float s1 = c1 + __shfl_xor(c1, 32);
            total = (g & 4) ? s1 : s0;
        }

        float v = fast_tanh(fmaf(dd, total, bias_c));
        out[(size_t)d * OUT_CH + cidx] = v;  // 64 lanes cover one contiguous 256B row
        ssum += v;
        ssq += v * v;

        d = dn;
    }
#undef ISSUE
#undef CONSUME

    __shared__ float ls[256];
    __shared__ float ls2[256];
    ls[t] = ssum; ls2[t] = ssq;
    __syncthreads();
    if (t < 128) { ls[t] += ls[t + 128]; ls2[t] += ls2[t + 128]; }
    __syncthreads();
    if (t < 64) {
        // lane==t here, so cidx is this thread's channel; same-channel partials fold correctly
        atomicAdd(&sums[cidx], ls[t] + ls[t + 64]);
        atomicAdd(&sums[64 + cidx], ls2[t] + ls2[t + 64]);
    }
}

// ---------------- BN apply in place (float4) ----------------
__global__ __launch_bounds__(256) void bn_apply_kernel(float4* __restrict__ a,
                                                       const float* __restrict__ sums,
                                                       const float* __restrict__ gamma,
                                                       const float* __restrict__ beta, int total4) {
    int c0 = (threadIdx.x * 4) & 63;
    const float invN = 1.0f / (float)N_NODES;
    float4 scale, shift;
    {
        float m0 = sums[c0 + 0] * invN, m1 = sums[c0 + 1] * invN;
        float m2 = sums[c0 + 2] * invN, m3 = sums[c0 + 3] * invN;
        float v0 = sums[64 + c0 + 0] * invN - m0 * m0;
        float v1 = sums[64 + c0 + 1] * invN - m1 * m1;
        float v2 = sums[64 + c0 + 2] * invN - m2 * m2;
        float v3 = sums[64 + c0 + 3] * invN - m3 * m3;
        scale.x = gamma[c0 + 0] * rsqrtf(v0 + BN_EPS);
        scale.y = gamma[c0 + 1] * rsqrtf(v1 + BN_EPS);
        scale.z = gamma[c0 + 2] * rsqrtf(v2 + BN_EPS);
        scale.w = gamma[c0 + 3] * rsqrtf(v3 + BN_EPS);
        shift.x = beta[c0 + 0] - m0 * scale.x;
        shift.y = beta[c0 + 1] - m1 * scale.y;
        shift.z = beta[c0 + 2] - m2 * scale.z;
        shift.w = beta[c0 + 3] - m3 * scale.w;
    }
    int stride = gridDim.x * blockDim.x;
    for (int idx = blockIdx.x * blockDim.x + threadIdx.x; idx < total4; idx += stride) {
        float4 v = a[idx];
        v.x = v.x * scale.x + shift.x;
        v.y = v.y * scale.y + shift.y;
        v.z = v.z * scale.z + shift.z;
        v.w = v.w * scale.w + shift.w;
        a[idx] = v;
    }
}

extern "C" void kernel_launch(void* const* d_in, const int* in_sizes, int n_in,
                              void* d_out, int out_size, void* d_ws, size_t ws_size,
                              hipStream_t stream) {
    const float* x     = (const float*)d_in[0];
    const int*   eidx  = (const int*)d_in[1];   // [2, E] flat: src row then dst row
    const float* W     = (const float*)d_in[2];
    const float* bias  = (const float*)d_in[3];
    const float* gamma = (const float*)d_in[4];
    const float* beta  = (const float*)d_in[5];
    float* out = (float*)d_out;

    const int4* esrc4 = (const int4*)eidx;
    const int4* edst4 = (const int4*)(eidx + N_EDGES);

    // workspace layout (cnt..hb contiguous so ONE memset zeroes cnt + sums + hb pad row):
    // slot[N*CAP] ushort (6.4MB) | cnt[N] i32 | sums[128] f32 | hb[(N+1)*64] bf16 (6.4MB)
    ushort* slot = (ushort*)d_ws;
    int*   cnt   = (int*)(slot + (size_t)N_NODES * CAP);
    float* sums  = (float*)(cnt + N_NODES);
    ushort* hb   = (ushort*)(sums + 128);

    size_t zero_span = (size_t)N_NODES * 4 + 128 * 4 + (size_t)(N_NODES + 1) * OUT_CH * 2;
    hipMemsetAsync(cnt, 0, zero_span, stream);
    fill_slots_kernel<<<(N_EDGES / 4 + 255) / 256, 256, 0, stream>>>(esrc4, edst4, cnt, slot, N_EDGES / 4);
    gemm_mfma_kernel<<<(N_NODES + 63) / 64, 256, 0, stream>>>(x, W, cnt, hb, N_NODES);
    gather_fused_kernel<<<2048, 256, 0, stream>>>(cnt, slot, hb, bias, out, sums, N_NODES);
    bn_apply_kernel<<<512, 256, 0, stream>>>((float4*)out, sums, gamma, beta, N_NODES * OUT_CH / 4);
}

// Round 6
// 202.201 us; speedup vs baseline: 1.0295x; 1.0295x over previous
//
#include <hip/hip_runtime.h>
#include <hip/hip_bf16.h>
#include <math.h>

#define N_NODES 50000
#define N_EDGES 800000
#define IN_CH 128
#define OUT_CH 64
#define BN_EPS 1e-5f
#define CAP 64  // max in-degree slots; P(deg>64) ~ e^-40 for 800k edges into 50k nodes

typedef __attribute__((ext_vector_type(8))) short short8;
typedef __attribute__((ext_vector_type(4))) float f32x4;

__device__ __forceinline__ float bf16u_to_f32(uint u) { return __uint_as_float(u << 16); }

__device__ __forceinline__ ushort f32_to_bf16(float f) {
    uint u = __float_as_uint(f);
    uint r = (u + 0x7fff + ((u >> 16) & 1)) >> 16;  // RNE
    return (ushort)r;
}

// tanh(x) = (e^2x - 1)/(e^2x + 1) via v_exp_f32 (2^x) + v_rcp_f32. ~1e-6 abs error,
// negligible vs the 0.0176 bf16 floor. Clamp arg: tanh(30)==1.0f in fp32, avoids inf/inf.
__device__ __forceinline__ float fast_tanh(float x) {
    float xa = fminf(x, 30.0f);
    float e;
    asm("v_exp_f32 %0, %1" : "=v"(e) : "v"(xa * 2.8853900817779268f));  // e^{2x} = 2^{2x*log2(e)}
    float inv;
    asm("v_rcp_f32 %0, %1" : "=v"(inv) : "v"(e + 1.0f));
    return (e - 1.0f) * inv;
}

// ---------------- fill slot table: slot[d*CAP + pos] = src (ushort) ----------------
// 1 edge/thread (3125 blocks): 781-block int4 version capped at ~12 waves/CU; full residency
// gives ~2.7x more atomics in flight on this latency-bound kernel. Plain stores: L2 merges
// the scattered 2B stores (NT stores forced partial-line HBM writebacks, 46MB WRITE_SIZE).
__global__ void fill_slots_kernel(const int* __restrict__ esrc, const int* __restrict__ edst,
                                  int* __restrict__ cnt, ushort* __restrict__ slot, int E) {
    int i = blockIdx.x * blockDim.x + threadIdx.x;
    if (i < E) {
        int s = esrc[i];
        int d = edst[i];
        int p = atomicAdd(&cnt[d], 1);
        if (p < CAP) slot[d * CAP + p] = (ushort)s;
    }
}

// ---------------- MFMA GEMM: hb[N,64](bf16) = bf16(x[N,128]) @ bf16(W[128,64]) * rsqrt(cnt+1) --
// dinv[src] folded into hb so the gather inner loop is a pure row-sum. dinv computed from cnt
// directly (rsqrtf is deterministic -> bitwise-identical to a precomputed array).
// XPAD=136: row stride = 17 x 16B granules (odd) -> ds_read_b128 conflict-free.
#define XPAD 136
__global__ __launch_bounds__(256) void gemm_mfma_kernel(const float* __restrict__ x,
                                                        const float* __restrict__ W,
                                                        const int* __restrict__ cnt,
                                                        ushort* __restrict__ hb, int N) {
    __shared__ ushort xs[64 * XPAD];
    __shared__ ushort wt[64 * XPAD];   // W^T: wt[n][k]
    int t = threadIdx.x;
    int lane = t & 63;
    int w = t >> 6;
    int nn = lane & 15;
    int quad = lane >> 4;
    int row0 = blockIdx.x * 64;

    // W staging: 8 x float4 loads (vs 32 scalar) per thread
    const float4* W4 = (const float4*)W;
#pragma unroll
    for (int i = 0; i < 8; ++i) {
        int f4 = t + 256 * i;
        float4 v = W4[f4];
        int e0 = f4 * 4;
        int k = e0 >> 6;
        int n = e0 & 63;   // 4 consecutive n at the same k
        wt[(n + 0) * XPAD + k] = f32_to_bf16(v.x);
        wt[(n + 1) * XPAD + k] = f32_to_bf16(v.y);
        wt[(n + 2) * XPAD + k] = f32_to_bf16(v.z);
        wt[(n + 3) * XPAD + k] = f32_to_bf16(v.w);
    }
#pragma unroll
    for (int i = 0; i < 8; ++i) {
        int linear4 = t + 256 * i;
        int r = linear4 >> 5;
        int c4 = linear4 & 31;
        int gr = row0 + r; if (gr >= N) gr = N - 1;
        float4 v = *(const float4*)(x + (size_t)gr * IN_CH + c4 * 4);
        ushort u0 = f32_to_bf16(v.x), u1 = f32_to_bf16(v.y);
        ushort u2 = f32_to_bf16(v.z), u3 = f32_to_bf16(v.w);
        uint2 packed = make_uint2((uint)u0 | ((uint)u1 << 16), (uint)u2 | ((uint)u3 << 16));
        *(uint2*)&xs[r * XPAD + c4 * 4] = packed;
    }
    __syncthreads();

    short8 bfrag[4][4];
#pragma unroll
    for (int t2 = 0; t2 < 4; ++t2)
#pragma unroll
        for (int c = 0; c < 4; ++c)
            bfrag[t2][c] = *(const short8*)&wt[(16 * t2 + nn) * XPAD + 32 * c + quad * 8];

    f32x4 acc[4] = {{0.f, 0.f, 0.f, 0.f}, {0.f, 0.f, 0.f, 0.f},
                    {0.f, 0.f, 0.f, 0.f}, {0.f, 0.f, 0.f, 0.f}};
#pragma unroll
    for (int c = 0; c < 4; ++c) {
        short8 afrag = *(const short8*)&xs[(16 * w + nn) * XPAD + 32 * c + quad * 8];
#pragma unroll
        for (int t2 = 0; t2 < 4; ++t2)
            acc[t2] = __builtin_amdgcn_mfma_f32_16x16x32_bf16(afrag, bfrag[t2][c], acc[t2], 0, 0, 0);
    }

    int rbase = row0 + 16 * w + quad * 4;
    float dv[4];
#pragma unroll
    for (int r = 0; r < 4; ++r)
        dv[r] = (rbase + r < N) ? rsqrtf((float)(cnt[rbase + r] + 1)) : 0.f;
#pragma unroll
    for (int t2 = 0; t2 < 4; ++t2) {
#pragma unroll
        for (int r = 0; r < 4; ++r) {
            int row = rbase + r;
            if (row < N) hb[(size_t)row * OUT_CH + 16 * t2 + nn] = f32_to_bf16(acc[t2][r] * dv[r]);
        }
    }
}

// ---------------- fused gather: 8 groups x 8 lanes, uint4 row loads (8 edges/instr) ----------
// EXACT round-1 loop structure (measured 55us, VGPR 52, VALUBusy 30%): the while-loop +
// cross-node-prefetch restructure steered the allocator to a 32-VGPR serialized schedule
// (16% VALUBusy, 66us) even WITHOUT a launch bound -- reverted. Only local substitutions:
// fast_tanh, and dd from cnt (one load instead of dinv+cnt).
// Item 0 = self-loop, items 1..m = slot entries; out-of-range items read zeroed row hb[N].
__global__ __launch_bounds__(256) void gather_fused_kernel(const int* __restrict__ cnt,
                                                           const ushort* __restrict__ slot,
                                                           const ushort* __restrict__ hb,
                                                           const float* __restrict__ bias,
                                                           float* __restrict__ out,
                                                           float* __restrict__ sums, int N) {
    int t = threadIdx.x;
    int lane = t & 63;
    int g = lane >> 3;
    int sub = lane & 7;
    // channel this lane owns after the reducing exchange (3-bit reversal of g)
    int cidx = 8 * sub + (((g & 1) << 2) | (g & 2) | ((g >> 2) & 1));
    int wid = (blockIdx.x * blockDim.x + t) >> 6;
    int nw = (gridDim.x * blockDim.x) >> 6;
    float bias_c = bias[cidx];
    float ssum = 0.f, ssq = 0.f;

#define ISSUE(J, H0, H1) do {                                              \
        int e0 = (J) + g, e1 = e0 + 8;                                     \
        int i0 = e0 - 1; i0 = (i0 < 0) ? 0 : i0;                           \
        int s0 = __shfl(sv, i0);                                           \
        int s1 = __shfl(sv, e1 - 1);                                       \
        s0 = (e0 == 0) ? d : s0;                                           \
        s0 = (e0 < M) ? s0 : N_NODES;                                      \
        s1 = (e1 < M) ? s1 : N_NODES;                                      \
        H0 = *(const uint4*)(hb + ((size_t)s0 << 6) + (sub << 3));         \
        H1 = *(const uint4*)(hb + ((size_t)s1 << 6) + (sub << 3));         \
    } while (0)

#define CONSUME(H)                                                          \
        a0 += __uint_as_float((H).x << 16); a1 += __uint_as_float((H).x & 0xffff0000u); \
        a2 += __uint_as_float((H).y << 16); a3 += __uint_as_float((H).y & 0xffff0000u); \
        a4 += __uint_as_float((H).z << 16); a5 += __uint_as_float((H).z & 0xffff0000u); \
        a6 += __uint_as_float((H).w << 16); a7 += __uint_as_float((H).w & 0xffff0000u);

    for (int d = wid; d < N; d += nw) {
        int mraw = cnt[d];
        float dd = rsqrtf((float)(mraw + 1));      // raw degree for normalization
        int m = mraw; if (m > CAP) m = CAP;        // clamp only for slot iteration
        int M = m + 1;  // +1: self-loop at item 0
        int sv = __builtin_nontemporal_load(&slot[(size_t)d * CAP + lane]);

        float a0 = 0.f, a1 = 0.f, a2 = 0.f, a3 = 0.f;
        float a4 = 0.f, a5 = 0.f, a6 = 0.f, a7 = 0.f;

        uint4 h0, h1;
        ISSUE(0, h0, h1);
        for (int j = 16; j < M; j += 16) {
            uint4 n0, n1;
            ISSUE(j, n0, n1);           // next block's loads fly while we consume
            CONSUME(h0); CONSUME(h1);
            h0 = n0; h1 = n1;
        }
        CONSUME(h0); CONSUME(h1);

        // reducing exchange across the 8 groups: 3 xor rounds, ends with 1 channel/lane
        float b0, b1, b2, b3;
        {
            float s0 = a0 + __shfl_xor(a0, 8);
            float s1 = a1 + __shfl_xor(a1, 8);
            float s2 = a2 + __shfl_xor(a2, 8);
            float s3 = a3 + __shfl_xor(a3, 8);
            float s4 = a4 + __shfl_xor(a4, 8);
            float s5 = a5 + __shfl_xor(a5, 8);
            float s6 = a6 + __shfl_xor(a6, 8);
            float s7 = a7 + __shfl_xor(a7, 8);
            bool hi = (g & 1);
            b0 = hi ? s4 : s0; b1 = hi ? s5 : s1; b2 = hi ? s6 : s2; b3 = hi ? s7 : s3;
        }
        float c0, c1;
        {
            float s0 = b0 + __shfl_xor(b0, 16);
            float s1 = b1 + __shfl_xor(b1, 16);
            float s2 = b2 + __shfl_xor(b2, 16);
            float s3 = b3 + __shfl_xor(b3, 16);
            bool hi = (g & 2);
            c0 = hi ? s2 : s0; c1 = hi ? s3 : s1;
        }
        float total;
        {
            float s0 = c0 + __shfl_xor(c0, 32);
            float s1 = c1 + __shfl_xor(c1, 32);
            total = (g & 4) ? s1 : s0;
        }

        float v = fast_tanh(fmaf(dd, total, bias_c));
        out[(size_t)d * OUT_CH + cidx] = v;  // 64 lanes cover one contiguous 256B row
        ssum += v;
        ssq += v * v;
    }
#undef ISSUE
#undef CONSUME

    __shared__ float ls[256];
    __shared__ float ls2[256];
    ls[t] = ssum; ls2[t] = ssq;
    __syncthreads();
    if (t < 128) { ls[t] += ls[t + 128]; ls2[t] += ls2[t + 128]; }
    __syncthreads();
    if (t < 64) {
        // lane==t here, so cidx is this thread's channel; same-channel partials fold correctly
        atomicAdd(&sums[cidx], ls[t] + ls[t + 64]);
        atomicAdd(&sums[64 + cidx], ls2[t] + ls2[t + 64]);
    }
}

// ---------------- BN apply in place (float4) ----------------
__global__ __launch_bounds__(256) void bn_apply_kernel(float4* __restrict__ a,
                                                       const float* __restrict__ sums,
                                                       const float* __restrict__ gamma,
                                                       const float* __restrict__ beta, int total4) {
    int c0 = (threadIdx.x * 4) & 63;
    const float invN = 1.0f / (float)N_NODES;
    float4 scale, shift;
    {
        float m0 = sums[c0 + 0] * invN, m1 = sums[c0 + 1] * invN;
        float m2 = sums[c0 + 2] * invN, m3 = sums[c0 + 3] * invN;
        float v0 = sums[64 + c0 + 0] * invN - m0 * m0;
        float v1 = sums[64 + c0 + 1] * invN - m1 * m1;
        float v2 = sums[64 + c0 + 2] * invN - m2 * m2;
        float v3 = sums[64 + c0 + 3] * invN - m3 * m3;
        scale.x = gamma[c0 + 0] * rsqrtf(v0 + BN_EPS);
        scale.y = gamma[c0 + 1] * rsqrtf(v1 + BN_EPS);
        scale.z = gamma[c0 + 2] * rsqrtf(v2 + BN_EPS);
        scale.w = gamma[c0 + 3] * rsqrtf(v3 + BN_EPS);
        shift.x = beta[c0 + 0] - m0 * scale.x;
        shift.y = beta[c0 + 1] - m1 * scale.y;
        shift.z = beta[c0 + 2] - m2 * scale.z;
        shift.w = beta[c0 + 3] - m3 * scale.w;
    }
    int stride = gridDim.x * blockDim.x;
    for (int idx = blockIdx.x * blockDim.x + threadIdx.x; idx < total4; idx += stride) {
        float4 v = a[idx];
        v.x = v.x * scale.x + shift.x;
        v.y = v.y * scale.y + shift.y;
        v.z = v.z * scale.z + shift.z;
        v.w = v.w * scale.w + shift.w;
        a[idx] = v;
    }
}

extern "C" void kernel_launch(void* const* d_in, const int* in_sizes, int n_in,
                              void* d_out, int out_size, void* d_ws, size_t ws_size,
                              hipStream_t stream) {
    const float* x     = (const float*)d_in[0];
    const int*   eidx  = (const int*)d_in[1];   // [2, E] flat: src row then dst row
    const float* W     = (const float*)d_in[2];
    const float* bias  = (const float*)d_in[3];
    const float* gamma = (const float*)d_in[4];
    const float* beta  = (const float*)d_in[5];
    float* out = (float*)d_out;

    const int* esrc = eidx;
    const int* edst = eidx + N_EDGES;

    // workspace layout -- hb FIRST so its 128B rows are cache-line aligned (round-4 layout put
    // hb at offset 64 mod 128: every row gather touched 2 lines, FETCH 34->52MB):
    // hb[(N+1)*64] bf16 (6.4MB, row N = zeros) | cnt[N] i32 | sums[128] f32 | slot (256B-aligned)
    ushort* hb   = (ushort*)d_ws;
    int*   cnt   = (int*)(hb + (size_t)(N_NODES + 1) * OUT_CH);
    float* sums  = (float*)(cnt + N_NODES);
    ushort* slot = (ushort*)(((uintptr_t)(sums + 128) + 255) & ~(uintptr_t)255);

    // one memset covers hb pad row (last 128B of hb, contiguous with cnt) + cnt + sums
    size_t zero_span = (size_t)OUT_CH * 2 + (size_t)N_NODES * 4 + 128 * 4;
    hipMemsetAsync(hb + (size_t)N_NODES * OUT_CH, 0, zero_span, stream);
    fill_slots_kernel<<<(N_EDGES + 255) / 256, 256, 0, stream>>>(esrc, edst, cnt, slot, N_EDGES);
    gemm_mfma_kernel<<<(N_NODES + 63) / 64, 256, 0, stream>>>(x, W, cnt, hb, N_NODES);
    gather_fused_kernel<<<2048, 256, 0, stream>>>(cnt, slot, hb, bias, out, sums, N_NODES);
    bn_apply_kernel<<<512, 256, 0, stream>>>((float4*)out, sums, gamma, beta, N_NODES * OUT_CH / 4);
}

// Round 7
// 201.465 us; speedup vs baseline: 1.0333x; 1.0037x over previous
//
#include <hip/hip_runtime.h>
#include <hip/hip_bf16.h>
#include <math.h>

#define N_NODES 50000
#define N_EDGES 800000
#define IN_CH 128
#define OUT_CH 64
#define BN_EPS 1e-5f
#define CAP 64  // max in-degree slots; P(deg>64) ~ e^-40 for 800k edges into 50k nodes

typedef __attribute__((ext_vector_type(8))) short short8;
typedef __attribute__((ext_vector_type(4))) float f32x4;

__device__ __forceinline__ float bf16u_to_f32(uint u) { return __uint_as_float(u << 16); }

__device__ __forceinline__ ushort f32_to_bf16(float f) {
    uint u = __float_as_uint(f);
    uint r = (u + 0x7fff + ((u >> 16) & 1)) >> 16;  // RNE
    return (ushort)r;
}

// ---------------- fill slot table: slot[d*CAP + pos] = src (ushort) ----------------
// 1 edge/thread (3125 blocks) for full wave residency on this atomic-latency-bound kernel.
// Plain stores: L2 merges scattered 2B stores (NT stores -> partial-line writebacks, 46MB).
__global__ void fill_slots_kernel(const int* __restrict__ esrc, const int* __restrict__ edst,
                                  int* __restrict__ cnt, ushort* __restrict__ slot, int E) {
    int i = blockIdx.x * blockDim.x + threadIdx.x;
    if (i < E) {
        int s = esrc[i];
        int d = edst[i];
        int p = atomicAdd(&cnt[d], 1);
        if (p < CAP) slot[d * CAP + p] = (ushort)s;
    }
}

// ---------------- MFMA GEMM: hb[N,64](bf16) = bf16(x[N,128]) @ bf16(W[128,64]) * rsqrt(cnt+1) --
// dinv[src] folded into hb so the gather inner loop is a pure row-sum. Also WRITES dinv[row]
// (nn==0 lanes) so the gather can load it -- restoring the exact round-1 gather code that
// measured 55us/VGPR52. XPAD=136: odd 16B-granule stride -> ds_read_b128 conflict-free.
#define XPAD 136
__global__ __launch_bounds__(256) void gemm_mfma_kernel(const float* __restrict__ x,
                                                        const float* __restrict__ W,
                                                        const int* __restrict__ cnt,
                                                        ushort* __restrict__ hb,
                                                        float* __restrict__ dinv, int N) {
    __shared__ ushort xs[64 * XPAD];
    __shared__ ushort wt[64 * XPAD];   // W^T: wt[n][k]
    int t = threadIdx.x;
    int lane = t & 63;
    int w = t >> 6;
    int nn = lane & 15;
    int quad = lane >> 4;
    int row0 = blockIdx.x * 64;

    // W staging: 8 x float4 loads (vs 32 scalar) per thread
    const float4* W4 = (const float4*)W;
#pragma unroll
    for (int i = 0; i < 8; ++i) {
        int f4 = t + 256 * i;
        float4 v = W4[f4];
        int e0 = f4 * 4;
        int k = e0 >> 6;
        int n = e0 & 63;   // 4 consecutive n at the same k
        wt[(n + 0) * XPAD + k] = f32_to_bf16(v.x);
        wt[(n + 1) * XPAD + k] = f32_to_bf16(v.y);
        wt[(n + 2) * XPAD + k] = f32_to_bf16(v.z);
        wt[(n + 3) * XPAD + k] = f32_to_bf16(v.w);
    }
#pragma unroll
    for (int i = 0; i < 8; ++i) {
        int linear4 = t + 256 * i;
        int r = linear4 >> 5;
        int c4 = linear4 & 31;
        int gr = row0 + r; if (gr >= N) gr = N - 1;
        float4 v = *(const float4*)(x + (size_t)gr * IN_CH + c4 * 4);
        ushort u0 = f32_to_bf16(v.x), u1 = f32_to_bf16(v.y);
        ushort u2 = f32_to_bf16(v.z), u3 = f32_to_bf16(v.w);
        uint2 packed = make_uint2((uint)u0 | ((uint)u1 << 16), (uint)u2 | ((uint)u3 << 16));
        *(uint2*)&xs[r * XPAD + c4 * 4] = packed;
    }
    __syncthreads();

    short8 bfrag[4][4];
#pragma unroll
    for (int t2 = 0; t2 < 4; ++t2)
#pragma unroll
        for (int c = 0; c < 4; ++c)
            bfrag[t2][c] = *(const short8*)&wt[(16 * t2 + nn) * XPAD + 32 * c + quad * 8];

    f32x4 acc[4] = {{0.f, 0.f, 0.f, 0.f}, {0.f, 0.f, 0.f, 0.f},
                    {0.f, 0.f, 0.f, 0.f}, {0.f, 0.f, 0.f, 0.f}};
#pragma unroll
    for (int c = 0; c < 4; ++c) {
        short8 afrag = *(const short8*)&xs[(16 * w + nn) * XPAD + 32 * c + quad * 8];
#pragma unroll
        for (int t2 = 0; t2 < 4; ++t2)
            acc[t2] = __builtin_amdgcn_mfma_f32_16x16x32_bf16(afrag, bfrag[t2][c], acc[t2], 0, 0, 0);
    }

    int rbase = row0 + 16 * w + quad * 4;
    float dv[4];
#pragma unroll
    for (int r = 0; r < 4; ++r)
        dv[r] = (rbase + r < N) ? rsqrtf((float)(cnt[rbase + r] + 1)) : 0.f;
    if (nn == 0) {  // each row covered exactly once across (w,quad,r)
#pragma unroll
        for (int r = 0; r < 4; ++r)
            if (rbase + r < N) dinv[rbase + r] = dv[r];
    }
#pragma unroll
    for (int t2 = 0; t2 < 4; ++t2) {
#pragma unroll
        for (int r = 0; r < 4; ++r) {
            int row = rbase + r;
            if (row < N) hb[(size_t)row * OUT_CH + 16 * t2 + nn] = f32_to_bf16(acc[t2][r] * dv[r]);
        }
    }
}

// ---------------- fused gather: 8 groups x 8 lanes, uint4 row loads (8 edges/instr) ----------
// BYTE-IDENTICAL to the round-1 kernel that measured 55us / VGPR 52 / VALUBusy 30%.
// Subsequent "local" substitutions (inline-asm fast_tanh, rsqrt-from-cnt) collapsed the
// allocator to a 32-VGPR serialized schedule (16% VALUBusy, 63-66us) across THREE structural
// variants -- libm tanhf's register pressure appears to be what keeps the 2-deep ISSUE
// pipeline hoisted. Do not "optimize" tanh here without re-measuring VGPR.
__global__ __launch_bounds__(256) void gather_fused_kernel(const int* __restrict__ cnt,
                                                           const ushort* __restrict__ slot,
                                                           const float* __restrict__ dinv,
                                                           const ushort* __restrict__ hb,
                                                           const float* __restrict__ bias,
                                                           float* __restrict__ out,
                                                           float* __restrict__ sums, int N) {
    int t = threadIdx.x;
    int lane = t & 63;
    int g = lane >> 3;
    int sub = lane & 7;
    // channel this lane owns after the reducing exchange (3-bit reversal of g)
    int cidx = 8 * sub + (((g & 1) << 2) | (g & 2) | ((g >> 2) & 1));
    int wid = (blockIdx.x * blockDim.x + t) >> 6;
    int nw = (gridDim.x * blockDim.x) >> 6;
    float bias_c = bias[cidx];
    float ssum = 0.f, ssq = 0.f;

#define ISSUE(J, H0, H1) do {                                              \
        int e0 = (J) + g, e1 = e0 + 8;                                     \
        int i0 = e0 - 1; i0 = (i0 < 0) ? 0 : i0;                           \
        int s0 = __shfl(sv, i0);                                           \
        int s1 = __shfl(sv, e1 - 1);                                       \
        s0 = (e0 == 0) ? d : s0;                                           \
        s0 = (e0 < M) ? s0 : N_NODES;                                      \
        s1 = (e1 < M) ? s1 : N_NODES;                                      \
        H0 = *(const uint4*)(hb + ((size_t)s0 << 6) + (sub << 3));         \
        H1 = *(const uint4*)(hb + ((size_t)s1 << 6) + (sub << 3));         \
    } while (0)

#define CONSUME(H)                                                          \
        a0 += __uint_as_float((H).x << 16); a1 += __uint_as_float((H).x & 0xffff0000u); \
        a2 += __uint_as_float((H).y << 16); a3 += __uint_as_float((H).y & 0xffff0000u); \
        a4 += __uint_as_float((H).z << 16); a5 += __uint_as_float((H).z & 0xffff0000u); \
        a6 += __uint_as_float((H).w << 16); a7 += __uint_as_float((H).w & 0xffff0000u);

    for (int d = wid; d < N; d += nw) {
        float dd = dinv[d];
        int m = cnt[d]; if (m > CAP) m = CAP;
        int M = m + 1;  // +1: self-loop at item 0
        int sv = __builtin_nontemporal_load(&slot[(size_t)d * CAP + lane]);

        float a0 = 0.f, a1 = 0.f, a2 = 0.f, a3 = 0.f;
        float a4 = 0.f, a5 = 0.f, a6 = 0.f, a7 = 0.f;

        uint4 h0, h1;
        ISSUE(0, h0, h1);
        for (int j = 16; j < M; j += 16) {
            uint4 n0, n1;
            ISSUE(j, n0, n1);           // next block's loads fly while we consume
            CONSUME(h0); CONSUME(h1);
            h0 = n0; h1 = n1;
        }
        CONSUME(h0); CONSUME(h1);

        // reducing exchange across the 8 groups: 3 xor rounds, ends with 1 channel/lane
        float b0, b1, b2, b3;
        {
            float s0 = a0 + __shfl_xor(a0, 8);
            float s1 = a1 + __shfl_xor(a1, 8);
            float s2 = a2 + __shfl_xor(a2, 8);
            float s3 = a3 + __shfl_xor(a3, 8);
            float s4 = a4 + __shfl_xor(a4, 8);
            float s5 = a5 + __shfl_xor(a5, 8);
            float s6 = a6 + __shfl_xor(a6, 8);
            float s7 = a7 + __shfl_xor(a7, 8);
            bool hi = (g & 1);
            b0 = hi ? s4 : s0; b1 = hi ? s5 : s1; b2 = hi ? s6 : s2; b3 = hi ? s7 : s3;
        }
        float c0, c1;
        {
            float s0 = b0 + __shfl_xor(b0, 16);
            float s1 = b1 + __shfl_xor(b1, 16);
            float s2 = b2 + __shfl_xor(b2, 16);
            float s3 = b3 + __shfl_xor(b3, 16);
            bool hi = (g & 2);
            c0 = hi ? s2 : s0; c1 = hi ? s3 : s1;
        }
        float total;
        {
            float s0 = c0 + __shfl_xor(c0, 32);
            float s1 = c1 + __shfl_xor(c1, 32);
            total = (g & 4) ? s1 : s0;
        }

        float v = tanhf(fmaf(dd, total, bias_c));
        out[(size_t)d * OUT_CH + cidx] = v;  // 64 lanes cover one contiguous 256B row
        ssum += v;
        ssq += v * v;
    }
#undef ISSUE
#undef CONSUME

    __shared__ float ls[256];
    __shared__ float ls2[256];
    ls[t] = ssum; ls2[t] = ssq;
    __syncthreads();
    if (t < 128) { ls[t] += ls[t + 128]; ls2[t] += ls2[t + 128]; }
    __syncthreads();
    if (t < 64) {
        // lane==t here, so cidx is this thread's channel; same-channel partials fold correctly
        atomicAdd(&sums[cidx], ls[t] + ls[t + 64]);
        atomicAdd(&sums[64 + cidx], ls2[t] + ls2[t + 64]);
    }
}

// ---------------- BN apply in place (float4) ----------------
__global__ __launch_bounds__(256) void bn_apply_kernel(float4* __restrict__ a,
                                                       const float* __restrict__ sums,
                                                       const float* __restrict__ gamma,
                                                       const float* __restrict__ beta, int total4) {
    int c0 = (threadIdx.x * 4) & 63;
    const float invN = 1.0f / (float)N_NODES;
    float4 scale, shift;
    {
        float m0 = sums[c0 + 0] * invN, m1 = sums[c0 + 1] * invN;
        float m2 = sums[c0 + 2] * invN, m3 = sums[c0 + 3] * invN;
        float v0 = sums[64 + c0 + 0] * invN - m0 * m0;
        float v1 = sums[64 + c0 + 1] * invN - m1 * m1;
        float v2 = sums[64 + c0 + 2] * invN - m2 * m2;
        float v3 = sums[64 + c0 + 3] * invN - m3 * m3;
        scale.x = gamma[c0 + 0] * rsqrtf(v0 + BN_EPS);
        scale.y = gamma[c0 + 1] * rsqrtf(v1 + BN_EPS);
        scale.z = gamma[c0 + 2] * rsqrtf(v2 + BN_EPS);
        scale.w = gamma[c0 + 3] * rsqrtf(v3 + BN_EPS);
        shift.x = beta[c0 + 0] - m0 * scale.x;
        shift.y = beta[c0 + 1] - m1 * scale.y;
        shift.z = beta[c0 + 2] - m2 * scale.z;
        shift.w = beta[c0 + 3] - m3 * scale.w;
    }
    int stride = gridDim.x * blockDim.x;
    for (int idx = blockIdx.x * blockDim.x + threadIdx.x; idx < total4; idx += stride) {
        float4 v = a[idx];
        v.x = v.x * scale.x + shift.x;
        v.y = v.y * scale.y + shift.y;
        v.z = v.z * scale.z + shift.z;
        v.w = v.w * scale.w + shift.w;
        a[idx] = v;
    }
}

extern "C" void kernel_launch(void* const* d_in, const int* in_sizes, int n_in,
                              void* d_out, int out_size, void* d_ws, size_t ws_size,
                              hipStream_t stream) {
    const float* x     = (const float*)d_in[0];
    const int*   eidx  = (const int*)d_in[1];   // [2, E] flat: src row then dst row
    const float* W     = (const float*)d_in[2];
    const float* bias  = (const float*)d_in[3];
    const float* gamma = (const float*)d_in[4];
    const float* beta  = (const float*)d_in[5];
    float* out = (float*)d_out;

    const int* esrc = eidx;
    const int* edst = eidx + N_EDGES;

    // workspace layout -- hb FIRST so its 128B rows are cache-line aligned:
    // hb[(N+1)*64] bf16 (6.4MB, row N = zeros) | cnt[N] i32 | sums[128] f32 |
    // slot[N*CAP] ushort (256B-aligned, 6.4MB) | dinv[N] f32
    ushort* hb   = (ushort*)d_ws;
    int*   cnt   = (int*)(hb + (size_t)(N_NODES + 1) * OUT_CH);
    float* sums  = (float*)(cnt + N_NODES);
    ushort* slot = (ushort*)(((uintptr_t)(sums + 128) + 255) & ~(uintptr_t)255);
    float* dinv  = (float*)(slot + (size_t)N_NODES * CAP);

    // one memset covers hb pad row (last 128B of hb, contiguous with cnt) + cnt + sums
    size_t zero_span = (size_t)OUT_CH * 2 + (size_t)N_NODES * 4 + 128 * 4;
    hipMemsetAsync(hb + (size_t)N_NODES * OUT_CH, 0, zero_span, stream);
    fill_slots_kernel<<<(N_EDGES + 255) / 256, 256, 0, stream>>>(esrc, edst, cnt, slot, N_EDGES);
    gemm_mfma_kernel<<<(N_NODES + 63) / 64, 256, 0, stream>>>(x, W, cnt, hb, dinv, N_NODES);
    gather_fused_kernel<<<2048, 256, 0, stream>>>(cnt, slot, dinv, hb, bias, out, sums, N_NODES);
    bn_apply_kernel<<<512, 256, 0, stream>>>((float4*)out, sums, gamma, beta, N_NODES * OUT_CH / 4);
}